// Round 4
// baseline (410.825 us; speedup 1.0000x reference)
//
#include <hip/hip_runtime.h>
#include <cstdint>

typedef __attribute__((ext_vector_type(8))) short short8;
typedef __attribute__((ext_vector_type(4))) float f32x4;
typedef unsigned short u16t;

// ---------- helpers ----------
__device__ __forceinline__ u16t f2bf(float f) {
  uint32_t u = __float_as_uint(f);
  u += 0x7fffu + ((u >> 16) & 1u);   // RNE
  return (u16t)(u >> 16);
}

__device__ __forceinline__ uint32_t cvtpk(float lo, float hi) {
  uint32_t r;
  asm("v_cvt_pk_bf16_f32 %0, %1, %2" : "=v"(r) : "v"(lo), "v"(hi));
  return r;
}

__device__ __forceinline__ void gload_lds16(const void* g, void* l) {
  __builtin_amdgcn_global_load_lds(
      (const __attribute__((address_space(1))) void*)g,
      (__attribute__((address_space(3))) void*)l, 16, 0, 0);
}

// ---------- f32 -> bf16 convert ----------
__global__ __launch_bounds__(256) void cvt_bf16_kernel(const float* __restrict__ in,
                                                       u16t* __restrict__ out, int n8) {
  int i = blockIdx.x * 256 + threadIdx.x;
  if (i >= n8) return;
  const float4* p = (const float4*)in + (size_t)i * 2;
  float4 a = p[0], b = p[1];
  union { short8 v; u16t e[8]; } r;
  r.e[0] = f2bf(a.x); r.e[1] = f2bf(a.y); r.e[2] = f2bf(a.z); r.e[3] = f2bf(a.w);
  r.e[4] = f2bf(b.x); r.e[5] = f2bf(b.y); r.e[6] = f2bf(b.z); r.e[7] = f2bf(b.w);
  *((short8*)out + i) = r.v;
}

// ---------- LayerNorm (row = 768 f32) -> bf16 ----------
__global__ __launch_bounds__(256) void ln_kernel(const float* __restrict__ x,
                                                 const float* __restrict__ g,
                                                 const float* __restrict__ b,
                                                 u16t* __restrict__ out) {
  int row = blockIdx.x, tid = threadIdx.x;
  int wave = tid >> 6, lane = tid & 63;
  const float* xr = x + (size_t)row * 768;
  float v0 = xr[tid], v1 = xr[tid + 256], v2 = xr[tid + 512];
  float s = v0 + v1 + v2;
  float q = v0 * v0 + v1 * v1 + v2 * v2;
#pragma unroll
  for (int m = 32; m >= 1; m >>= 1) {
    s += __shfl_xor(s, m, 64);
    q += __shfl_xor(q, m, 64);
  }
  __shared__ float red[8];
  if (lane == 0) { red[wave] = s; red[4 + wave] = q; }
  __syncthreads();
  s = red[0] + red[1] + red[2] + red[3];
  q = red[4] + red[5] + red[6] + red[7];
  float mu = s * (1.0f / 768.0f);
  float var = q * (1.0f / 768.0f) - mu * mu;
  float rs = rsqrtf(var + 1e-5f);
  u16t* orow = out + (size_t)row * 768;
  orow[tid]       = f2bf((v0 - mu) * rs * g[tid]       + b[tid]);
  orow[tid + 256] = f2bf((v1 - mu) * rs * g[tid + 256] + b[tid + 256]);
  orow[tid + 512] = f2bf((v2 - mu) * rs * g[tid + 512] + b[tid + 512]);
}

// ---------- GEMM: C[M,N] = A[M,K] @ W[N,K]^T  (bf16 in, fp32 acc) ----------
template <int EPI, int BM, int MINB>
__global__ __launch_bounds__(256, MINB) void gemm_bt(const u16t* __restrict__ A,
                                                     const u16t* __restrict__ W,
                                                     void* __restrict__ Cout,
                                                     const float* __restrict__ bias,
                                                     const float* __restrict__ res,
                                                     int M, int N, int K) {
  __shared__ __align__(16) u16t As[BM * 64];
  __shared__ __align__(16) u16t Bs[128 * 64];
  constexpr int MF = BM / 32;
  int tid = threadIdx.x;
  int wave = tid >> 6, lane = tid & 63;
  int wr = wave >> 1, wc = wave & 1;
  int bm = blockIdx.y * BM;
  int bn = blockIdx.x * 128;
  f32x4 acc[MF][4] = {};

  int lr = lane >> 3;
  int lc = lane & 7;
  int srcslot = lc ^ lr;
  const u16t* Abase = A + (size_t)(bm + lr) * K + srcslot * 8;
  const u16t* Wbase = W + (size_t)(bn + lr) * K + srcslot * 8;

  for (int kt = 0; kt < K; kt += 64) {
    __syncthreads();
#pragma unroll
    for (int i = 0; i < BM / 32; i++) {
      int chunk = wave * (BM / 32) + i;
      gload_lds16(Abase + (size_t)(chunk * 8) * K + kt, (void*)(As + chunk * 512));
    }
#pragma unroll
    for (int i = 0; i < 4; i++) {
      int chunk = wave * 4 + i;
      gload_lds16(Wbase + (size_t)(chunk * 8) * K + kt, (void*)(Bs + chunk * 512));
    }
    __syncthreads();

    short8 af[MF][2], bfr[4][2];
#pragma unroll
    for (int m = 0; m < MF; m++) {
      int row = wr * (BM / 2) + m * 16 + (lane & 15);
#pragma unroll
      for (int s = 0; s < 2; s++) {
        int slot = s * 4 + (lane >> 4);
        af[m][s] = *(const short8*)(As + row * 64 + ((slot ^ (row & 7)) * 8));
      }
    }
#pragma unroll
    for (int n = 0; n < 4; n++) {
      int row = wc * 64 + n * 16 + (lane & 15);
#pragma unroll
      for (int s = 0; s < 2; s++) {
        int slot = s * 4 + (lane >> 4);
        bfr[n][s] = *(const short8*)(Bs + row * 64 + ((slot ^ (row & 7)) * 8));
      }
    }
    __builtin_amdgcn_s_setprio(1);
#pragma unroll
    for (int m = 0; m < MF; m++)
#pragma unroll
      for (int n = 0; n < 4; n++) {
        acc[m][n] = __builtin_amdgcn_mfma_f32_16x16x32_bf16(af[m][0], bfr[n][0], acc[m][n], 0, 0, 0);
        acc[m][n] = __builtin_amdgcn_mfma_f32_16x16x32_bf16(af[m][1], bfr[n][1], acc[m][n], 0, 0, 0);
      }
    __builtin_amdgcn_s_setprio(0);
  }

#pragma unroll
  for (int m = 0; m < MF; m++) {
#pragma unroll
    for (int n = 0; n < 4; n++) {
      int r0 = bm + wr * (BM / 2) + m * 16 + (lane >> 4) * 4;
      int c = bn + wc * 64 + n * 16 + (lane & 15);
#pragma unroll
      for (int i = 0; i < 4; i++) {
        int r = r0 + i;
        float v = acc[m][n][i];
        if constexpr (EPI == 0) {
          ((u16t*)Cout)[(size_t)r * N + c] = f2bf(v);
        } else if constexpr (EPI == 1) {
          ((float*)Cout)[(size_t)r * N + c] = v + bias[c] + res[(size_t)r * N + c];
        } else {
          v += bias[c];
          float gl = 0.5f * v * (1.0f + erff(v * 0.70710678118f));
          ((u16t*)Cout)[(size_t)r * N + c] = f2bf(gl);
        }
      }
    }
  }
}

// ---------- V transpose: qkvb V-part -> vt[head][64][1024] ----------
__global__ __launch_bounds__(256) void vtrans_kernel(const u16t* __restrict__ qkv,
                                                     u16t* __restrict__ vt) {
  __shared__ u16t T[64][66];
  int h = blockIdx.x % 12, bb = blockIdx.x / 12, kt = blockIdx.y * 64;
  int t = threadIdx.x;
  int r = t >> 2, dc = t & 3;
  const u16t* src = qkv + (size_t)(bb * 1024 + kt + r) * 2304 + 1536 + h * 64 + dc * 16;
  union { uint4 u[2]; u16t e[16]; uint32_t w[8]; } buf;
  buf.u[0] = *(const uint4*)src;
  buf.u[1] = *(const uint4*)(src + 8);
#pragma unroll
  for (int j = 0; j < 8; j++)
    *(uint32_t*)&T[r][dc * 16 + 2 * j] = buf.w[j];
  __syncthreads();
  int d = t >> 2, kc = t & 3;
  union { uint4 u[2]; u16t e[16]; } o;
#pragma unroll
  for (int j = 0; j < 16; j++) o.e[j] = T[kc * 16 + j][d];
  u16t* dst = vt + ((size_t)blockIdx.x * 64 + d) * 1024 + kt + kc * 16;
  *(uint4*)dst = o.u[0];
  *(uint4*)(dst + 8) = o.u[1];
}

// ---------- barrier-free swapped-QK^T flash attention (16 q-rows / wave) ----------
// qkv: [B*N, 2304] bf16; vt: [96][64][1024] bf16; ctx: [B*N, 768] bf16
// grid: 1536 blocks x 256 thr; block = 4 independent waves, each 16 q-rows.
// S^T = mfma(K, Q): lane holds q = lane&15, k = n*16 + (lane>>4)*4 + i.
__global__ __launch_bounds__(256, 4) void attn_kernel(const u16t* __restrict__ qkv,
                                                      const u16t* __restrict__ vt,
                                                      u16t* __restrict__ ctx) {
  __shared__ __align__(16) u16t Plds[4][16 * 72];  // per-wave P^T, stride 72 u16
  int tid = threadIdx.x;
  int wave = tid >> 6, lane = tid & 63;
  int q = lane & 15, g = lane >> 4;

  // XCD swizzle: all 16 blocks of a head on one XCD (L2 reuse of K/V)
  int bid = blockIdx.x;
  int xcd = bid & 7, j = bid >> 3;          // j: 0..191
  int head = xcd + 8 * (j >> 4);            // 0..95
  int qt = (j & 15) * 64 + wave * 16;
  int b = head / 12, h = head % 12;

  const u16t* base = qkv + (size_t)b * 1024 * 2304 + h * 64;
  const u16t* kbase = base + 768;
  const u16t* vtb = vt + (size_t)head * 64 * 1024;

  // Q B-fragments: [d-half]
  short8 qf[2];
#pragma unroll
  for (int hh = 0; hh < 2; hh++)
    qf[hh] = *(const short8*)(base + (size_t)(qt + q) * 2304 + hh * 32 + g * 8);

  float m_ = -1e30f, l_ = 0.f;
  f32x4 o[4] = {};
  u16t* Pw = Plds[wave];

  for (int kt = 0; kt < 1024; kt += 64) {
    // K A-fragments
    short8 kf[4][2];
#pragma unroll
    for (int n = 0; n < 4; n++)
#pragma unroll
      for (int hh = 0; hh < 2; hh++)
        kf[n][hh] = *(const short8*)(kbase + (size_t)(kt + n * 16 + q) * 2304 + hh * 32 + g * 8);

    f32x4 s[4] = {};
    __builtin_amdgcn_s_setprio(1);
#pragma unroll
    for (int n = 0; n < 4; n++) {
      s[n] = __builtin_amdgcn_mfma_f32_16x16x32_bf16(kf[n][0], qf[0], s[n], 0, 0, 0);
      s[n] = __builtin_amdgcn_mfma_f32_16x16x32_bf16(kf[n][1], qf[1], s[n], 0, 0, 0);
    }
    __builtin_amdgcn_s_setprio(0);

    // V^T fragments (issued after QK so V latency hides under softmax;
    // kf registers are dead past this point)
    short8 vf[4][2];
#pragma unroll
    for (int n = 0; n < 4; n++)
#pragma unroll
      for (int hh = 0; hh < 2; hh++)
        vf[n][hh] = *(const short8*)(vtb + (size_t)(n * 16 + q) * 1024 + kt + hh * 32 + g * 8);

    // ---- online softmax for per-lane row q (tree reductions) ----
    float tn0 = fmaxf(fmaxf(s[0][0], s[0][1]), fmaxf(s[0][2], s[0][3]));
    float tn1 = fmaxf(fmaxf(s[1][0], s[1][1]), fmaxf(s[1][2], s[1][3]));
    float tn2 = fmaxf(fmaxf(s[2][0], s[2][1]), fmaxf(s[2][2], s[2][3]));
    float tn3 = fmaxf(fmaxf(s[3][0], s[3][1]), fmaxf(s[3][2], s[3][3]));
    float tm = fmaxf(fmaxf(tn0, tn1), fmaxf(tn2, tn3));
    tm = fmaxf(tm, __shfl_xor(tm, 16, 64));
    tm = fmaxf(tm, __shfl_xor(tm, 32, 64));
    float mnew = fmaxf(m_, tm);
    float alpha = __expf((m_ - mnew) * 0.125f);
    m_ = mnew;
#pragma unroll
    for (int n = 0; n < 4; n++)
#pragma unroll
      for (int i = 0; i < 4; i++)
        s[n][i] = __expf((s[n][i] - mnew) * 0.125f);
    float r0 = (s[0][0] + s[0][1]) + (s[0][2] + s[0][3]);
    float r1 = (s[1][0] + s[1][1]) + (s[1][2] + s[1][3]);
    float r2 = (s[2][0] + s[2][1]) + (s[2][2] + s[2][3]);
    float r3 = (s[3][0] + s[3][1]) + (s[3][2] + s[3][3]);
    float rs = (r0 + r1) + (r2 + r3);
    rs += __shfl_xor(rs, 16, 64);
    rs += __shfl_xor(rs, 32, 64);
    l_ = l_ * alpha + rs;

    // P -> LDS (bf16)
#pragma unroll
    for (int n = 0; n < 4; n++) {
      uint32_t w0 = cvtpk(s[n][0], s[n][1]);
      uint32_t w1 = cvtpk(s[n][2], s[n][3]);
      *(uint2*)(Pw + q * 72 + n * 16 + g * 4) = make_uint2(w0, w1);
    }

    // rescale O
#pragma unroll
    for (int n = 0; n < 4; n++)
#pragma unroll
      for (int i = 0; i < 4; i++) o[n][i] *= alpha;

    // PV: O^T += V^T-frag x P^T-frag  (same-wave LDS RAW -> lgkmcnt only)
    short8 pA[2];
#pragma unroll
    for (int hh = 0; hh < 2; hh++)
      pA[hh] = *(const short8*)(Pw + q * 72 + hh * 32 + g * 8);
    __builtin_amdgcn_s_setprio(1);
#pragma unroll
    for (int n = 0; n < 4; n++) {
      o[n] = __builtin_amdgcn_mfma_f32_16x16x32_bf16(vf[n][0], pA[0], o[n], 0, 0, 0);
      o[n] = __builtin_amdgcn_mfma_f32_16x16x32_bf16(vf[n][1], pA[1], o[n], 0, 0, 0);
    }
    __builtin_amdgcn_s_setprio(0);
  }

  float inv = 1.f / l_;
  u16t* crow = ctx + (size_t)(b * 1024 + qt + q) * 768 + h * 64;
#pragma unroll
  for (int n = 0; n < 4; n++) {
    uint32_t a0 = (uint32_t)f2bf(o[n][0] * inv) | ((uint32_t)f2bf(o[n][1] * inv) << 16);
    uint32_t a1 = (uint32_t)f2bf(o[n][2] * inv) | ((uint32_t)f2bf(o[n][3] * inv) << 16);
    *(uint32_t*)(crow + n * 16 + g * 4) = a0;
    *(uint32_t*)(crow + n * 16 + g * 4 + 2) = a1;
  }
}

// ---------- launch ----------
extern "C" void kernel_launch(void* const* d_in, const int* in_sizes, int n_in,
                              void* d_out, int out_size, void* d_ws, size_t ws_size,
                              hipStream_t stream) {
  const float* x      = (const float*)d_in[0];
  const float* ln1_g  = (const float*)d_in[1];
  const float* ln1_b  = (const float*)d_in[2];
  const float* qkv_w  = (const float*)d_in[3];
  const float* proj_w = (const float*)d_in[4];
  const float* proj_b = (const float*)d_in[5];
  const float* ln2_g  = (const float*)d_in[6];
  const float* ln2_b  = (const float*)d_in[7];
  const float* fc1_w  = (const float*)d_in[8];
  const float* fc1_b  = (const float*)d_in[9];
  const float* fc2_w  = (const float*)d_in[10];
  const float* fc2_b  = (const float*)d_in[11];

  char* ws = (char*)d_ws;
  u16t* h1   = (u16t*)(ws + 0);           // 8192x768 bf16 (ln1 out; REUSED as vt; then ln2 out)
  u16t* qkvb = (u16t*)(ws + 12582912);    // 8192x2304 bf16
  u16t* ctx  = (u16t*)(ws + 50331648);    // 8192x768 bf16
  float* x2  = (float*)(ws + 62914560);   // 8192x768 f32
  u16t* hid  = (u16t*)(ws + 88080384);    // 8192x3072 bf16
  u16t* wq   = (u16t*)(ws + 138412032);   // 2304x768 bf16
  u16t* wp   = (u16t*)(ws + 141950976);   // 768x768 bf16
  u16t* w1   = (u16t*)(ws + 143130624);   // 3072x768 bf16
  u16t* w2   = (u16t*)(ws + 147849216);   // 768x3072 bf16
  u16t* vtb  = h1;                        // 96x64x1024 bf16 = same 12.58MB, lifetime-disjoint
  float* out = (float*)d_out;

  cvt_bf16_kernel<<<864, 256, 0, stream>>>(qkv_w, wq, 221184);
  cvt_bf16_kernel<<<288, 256, 0, stream>>>(proj_w, wp, 73728);
  cvt_bf16_kernel<<<1152, 256, 0, stream>>>(fc1_w, w1, 294912);
  cvt_bf16_kernel<<<1152, 256, 0, stream>>>(fc2_w, w2, 294912);

  ln_kernel<<<8192, 256, 0, stream>>>(x, ln1_g, ln1_b, h1);
  gemm_bt<0, 128, 3><<<dim3(18, 64), 256, 0, stream>>>(h1, wq, qkvb, nullptr, nullptr, 8192, 2304, 768);
  vtrans_kernel<<<dim3(96, 16), 256, 0, stream>>>(qkvb, vtb);
  attn_kernel<<<1536, 256, 0, stream>>>(qkvb, vtb, ctx);
  gemm_bt<1, 64, 4><<<dim3(6, 128), 256, 0, stream>>>(ctx, wp, x2, proj_b, x, 8192, 768, 768);
  ln_kernel<<<8192, 256, 0, stream>>>(x2, ln2_g, ln2_b, h1);
  gemm_bt<2, 128, 3><<<dim3(24, 64), 256, 0, stream>>>(h1, w1, hid, fc1_b, nullptr, 8192, 3072, 768);
  gemm_bt<1, 64, 4><<<dim3(6, 128), 256, 0, stream>>>(hid, w2, out, fc2_b, x2, 8192, 768, 3072);
}

// Round 5
// 265.229 us; speedup vs baseline: 1.5489x; 1.5489x over previous
//
#include <hip/hip_runtime.h>
#include <cstdint>

typedef __attribute__((ext_vector_type(8))) short short8;
typedef __attribute__((ext_vector_type(4))) float f32x4;
typedef unsigned short u16t;

// ---------- helpers ----------
__device__ __forceinline__ u16t f2bf(float f) {
  uint32_t u = __float_as_uint(f);
  u += 0x7fffu + ((u >> 16) & 1u);   // RNE
  return (u16t)(u >> 16);
}

__device__ __forceinline__ uint32_t cvtpk(float lo, float hi) {
  uint32_t r;
  asm("v_cvt_pk_bf16_f32 %0, %1, %2" : "=v"(r) : "v"(lo), "v"(hi));
  return r;
}

__device__ __forceinline__ void gload_lds16(const void* g, void* l) {
  __builtin_amdgcn_global_load_lds(
      (const __attribute__((address_space(1))) void*)g,
      (__attribute__((address_space(3))) void*)l, 16, 0, 0);
}

// ---------- f32 -> bf16 convert ----------
__global__ __launch_bounds__(256) void cvt_bf16_kernel(const float* __restrict__ in,
                                                       u16t* __restrict__ out, int n8) {
  int i = blockIdx.x * 256 + threadIdx.x;
  if (i >= n8) return;
  const float4* p = (const float4*)in + (size_t)i * 2;
  float4 a = p[0], b = p[1];
  union { short8 v; u16t e[8]; } r;
  r.e[0] = f2bf(a.x); r.e[1] = f2bf(a.y); r.e[2] = f2bf(a.z); r.e[3] = f2bf(a.w);
  r.e[4] = f2bf(b.x); r.e[5] = f2bf(b.y); r.e[6] = f2bf(b.z); r.e[7] = f2bf(b.w);
  *((short8*)out + i) = r.v;
}

// ---------- LayerNorm (row = 768 f32) -> bf16 ----------
__global__ __launch_bounds__(256) void ln_kernel(const float* __restrict__ x,
                                                 const float* __restrict__ g,
                                                 const float* __restrict__ b,
                                                 u16t* __restrict__ out) {
  int row = blockIdx.x, tid = threadIdx.x;
  int wave = tid >> 6, lane = tid & 63;
  const float* xr = x + (size_t)row * 768;
  float v0 = xr[tid], v1 = xr[tid + 256], v2 = xr[tid + 512];
  float s = v0 + v1 + v2;
  float q = v0 * v0 + v1 * v1 + v2 * v2;
#pragma unroll
  for (int m = 32; m >= 1; m >>= 1) {
    s += __shfl_xor(s, m, 64);
    q += __shfl_xor(q, m, 64);
  }
  __shared__ float red[8];
  if (lane == 0) { red[wave] = s; red[4 + wave] = q; }
  __syncthreads();
  s = red[0] + red[1] + red[2] + red[3];
  q = red[4] + red[5] + red[6] + red[7];
  float mu = s * (1.0f / 768.0f);
  float var = q * (1.0f / 768.0f) - mu * mu;
  float rs = rsqrtf(var + 1e-5f);
  u16t* orow = out + (size_t)row * 768;
  orow[tid]       = f2bf((v0 - mu) * rs * g[tid]       + b[tid]);
  orow[tid + 256] = f2bf((v1 - mu) * rs * g[tid + 256] + b[tid + 256]);
  orow[tid + 512] = f2bf((v2 - mu) * rs * g[tid + 512] + b[tid + 512]);
}

// ---------- GEMM: C[M,N] = A[M,K] @ W[N,K]^T  (bf16 in, fp32 acc) ----------
template <int EPI, int BM, int MINB>
__global__ __launch_bounds__(256, MINB) void gemm_bt(const u16t* __restrict__ A,
                                                     const u16t* __restrict__ W,
                                                     void* __restrict__ Cout,
                                                     const float* __restrict__ bias,
                                                     const float* __restrict__ res,
                                                     int M, int N, int K) {
  __shared__ __align__(16) u16t As[BM * 64];
  __shared__ __align__(16) u16t Bs[128 * 64];
  constexpr int MF = BM / 32;
  int tid = threadIdx.x;
  int wave = tid >> 6, lane = tid & 63;
  int wr = wave >> 1, wc = wave & 1;
  int bm = blockIdx.y * BM;
  int bn = blockIdx.x * 128;
  f32x4 acc[MF][4] = {};

  int lr = lane >> 3;
  int lc = lane & 7;
  int srcslot = lc ^ lr;
  const u16t* Abase = A + (size_t)(bm + lr) * K + srcslot * 8;
  const u16t* Wbase = W + (size_t)(bn + lr) * K + srcslot * 8;

  for (int kt = 0; kt < K; kt += 64) {
    __syncthreads();
#pragma unroll
    for (int i = 0; i < BM / 32; i++) {
      int chunk = wave * (BM / 32) + i;
      gload_lds16(Abase + (size_t)(chunk * 8) * K + kt, (void*)(As + chunk * 512));
    }
#pragma unroll
    for (int i = 0; i < 4; i++) {
      int chunk = wave * 4 + i;
      gload_lds16(Wbase + (size_t)(chunk * 8) * K + kt, (void*)(Bs + chunk * 512));
    }
    __syncthreads();

    short8 af[MF][2], bfr[4][2];
#pragma unroll
    for (int m = 0; m < MF; m++) {
      int row = wr * (BM / 2) + m * 16 + (lane & 15);
#pragma unroll
      for (int s = 0; s < 2; s++) {
        int slot = s * 4 + (lane >> 4);
        af[m][s] = *(const short8*)(As + row * 64 + ((slot ^ (row & 7)) * 8));
      }
    }
#pragma unroll
    for (int n = 0; n < 4; n++) {
      int row = wc * 64 + n * 16 + (lane & 15);
#pragma unroll
      for (int s = 0; s < 2; s++) {
        int slot = s * 4 + (lane >> 4);
        bfr[n][s] = *(const short8*)(Bs + row * 64 + ((slot ^ (row & 7)) * 8));
      }
    }
    __builtin_amdgcn_s_setprio(1);
#pragma unroll
    for (int m = 0; m < MF; m++)
#pragma unroll
      for (int n = 0; n < 4; n++) {
        acc[m][n] = __builtin_amdgcn_mfma_f32_16x16x32_bf16(af[m][0], bfr[n][0], acc[m][n], 0, 0, 0);
        acc[m][n] = __builtin_amdgcn_mfma_f32_16x16x32_bf16(af[m][1], bfr[n][1], acc[m][n], 0, 0, 0);
      }
    __builtin_amdgcn_s_setprio(0);
  }

#pragma unroll
  for (int m = 0; m < MF; m++) {
#pragma unroll
    for (int n = 0; n < 4; n++) {
      int r0 = bm + wr * (BM / 2) + m * 16 + (lane >> 4) * 4;
      int c = bn + wc * 64 + n * 16 + (lane & 15);
#pragma unroll
      for (int i = 0; i < 4; i++) {
        int r = r0 + i;
        float v = acc[m][n][i];
        if constexpr (EPI == 0) {
          ((u16t*)Cout)[(size_t)r * N + c] = f2bf(v);
        } else if constexpr (EPI == 1) {
          ((float*)Cout)[(size_t)r * N + c] = v + bias[c] + res[(size_t)r * N + c];
        } else {
          v += bias[c];
          float gl = 0.5f * v * (1.0f + erff(v * 0.70710678118f));
          ((u16t*)Cout)[(size_t)r * N + c] = f2bf(gl);
        }
      }
    }
  }
}

// ---------- V transpose: qkvb V-part -> vt[head][64][1024] ----------
__global__ __launch_bounds__(256) void vtrans_kernel(const u16t* __restrict__ qkv,
                                                     u16t* __restrict__ vt) {
  __shared__ u16t T[64][66];
  int h = blockIdx.x % 12, bb = blockIdx.x / 12, kt = blockIdx.y * 64;
  int t = threadIdx.x;
  int r = t >> 2, dc = t & 3;
  const u16t* src = qkv + (size_t)(bb * 1024 + kt + r) * 2304 + 1536 + h * 64 + dc * 16;
  union { uint4 u[2]; u16t e[16]; uint32_t w[8]; } buf;
  buf.u[0] = *(const uint4*)src;
  buf.u[1] = *(const uint4*)(src + 8);
#pragma unroll
  for (int j = 0; j < 8; j++)
    *(uint32_t*)&T[r][dc * 16 + 2 * j] = buf.w[j];
  __syncthreads();
  int d = t >> 2, kc = t & 3;
  union { uint4 u[2]; u16t e[16]; } o;
#pragma unroll
  for (int j = 0; j < 16; j++) o.e[j] = T[kc * 16 + j][d];
  u16t* dst = vt + ((size_t)blockIdx.x * 64 + d) * 1024 + kt + kc * 16;
  *(uint4*)dst = o.u[0];
  *(uint4*)(dst + 8) = o.u[1];
}

// ---------- flash attention: block-shared LDS staging + 2-phase pipeline ----------
// qkv: [B*N, 2304] bf16; vt: [96][64][1024] bf16; ctx: [B*N, 768] bf16
// grid: 768 blocks x 256 thr; block = 128 q-rows (wave w owns [qt+w*32, +32)).
// Swapped QK^T: S^T = mfma(K, Q) -> lane holds q = lane&15, per-lane softmax.
__global__ __launch_bounds__(256, 3) void attn_kernel(const u16t* __restrict__ qkv,
                                                      const u16t* __restrict__ vt,
                                                      u16t* __restrict__ ctx) {
  __shared__ __align__(16) u16t Ks[2][64 * 64];    // K tile [k=64][d=64], XOR-swizzled slots
  __shared__ __align__(16) u16t Vs[2][64 * 64];    // V^T tile [d=64][k=64], XOR-swizzled
  __shared__ __align__(16) u16t Plds[4][32 * 72];  // per-wave P^T, stride 72 u16
  int tid = threadIdx.x;
  int wave = tid >> 6, lane = tid & 63;
  int q = lane & 15, g = lane >> 4;

  // XCD swizzle: all 8 q-blocks of a head land on one XCD (K/V L2 reuse)
  int bid = blockIdx.x;
  int xcd = bid & 7, j = bid >> 3;          // j: 0..95
  int head = xcd + 8 * (j >> 3);            // 0..95
  int qt = (j & 7) * 128 + wave * 32;
  int b = head / 12, h = head % 12;

  const u16t* base = qkv + (size_t)b * 1024 * 2304 + h * 64;
  const u16t* kbase = base + 768;
  const u16t* vtb = vt + (size_t)head * 64 * 1024;

  // Q B-fragments: [q-half][d-half]
  short8 qf[2][2];
#pragma unroll
  for (int hf = 0; hf < 2; hf++)
#pragma unroll
    for (int hh = 0; hh < 2; hh++)
      qf[hf][hh] = *(const short8*)(base + (size_t)(qt + hf * 16 + q) * 2304 + hh * 32 + g * 8);

  // staging source pointers (pre-swizzled slot so LDS-linear dest = swizzled layout)
  int lr = lane >> 3, lc = lane & 7;
  const u16t* ksrc = kbase + (size_t)lr * 2304 + (size_t)((lc ^ lr) * 8);
  const u16t* vsrc = vtb + (size_t)lr * 1024 + (size_t)((lc ^ lr) * 8);
  int c0 = wave * 2, c1 = wave * 2 + 1;   // this wave's 2 chunks (8 rows x 128B each)

  auto stage = [&](int kt, int buf) {
    gload_lds16(ksrc + (size_t)(kt + c0 * 8) * 2304, (void*)(Ks[buf] + c0 * 512));
    gload_lds16(ksrc + (size_t)(kt + c1 * 8) * 2304, (void*)(Ks[buf] + c1 * 512));
    gload_lds16(vsrc + (size_t)(c0 * 8) * 1024 + kt, (void*)(Vs[buf] + c0 * 512));
    gload_lds16(vsrc + (size_t)(c1 * 8) * 1024 + kt, (void*)(Vs[buf] + c1 * 512));
  };

  float mA = -1e30f, mB = -1e30f, lA = 0.f, lB = 0.f;
  f32x4 oA[4] = {}, oB[4] = {};
  u16t* Pw = Plds[wave];

  stage(0, 0);
  __syncthreads();

  for (int t = 0; t < 16; ++t) {
    int buf = t & 1;
    if (t < 15) stage((t + 1) * 64, buf ^ 1);   // issue next tile BEFORE compute

    const u16t* Kb = Ks[buf];
    const u16t* Vb = Vs[buf];

    // S^T = K x Q (per wave: 64 k x 32 q)
    f32x4 sA[4] = {}, sB[4] = {};
    __builtin_amdgcn_s_setprio(1);
#pragma unroll
    for (int n = 0; n < 4; n++) {
      int row = n * 16 + q;
      short8 k0 = *(const short8*)(Kb + row * 64 + ((g ^ (q & 7)) * 8));
      short8 k1 = *(const short8*)(Kb + row * 64 + (((4 + g) ^ (q & 7)) * 8));
      sA[n] = __builtin_amdgcn_mfma_f32_16x16x32_bf16(k0, qf[0][0], sA[n], 0, 0, 0);
      sA[n] = __builtin_amdgcn_mfma_f32_16x16x32_bf16(k1, qf[0][1], sA[n], 0, 0, 0);
      sB[n] = __builtin_amdgcn_mfma_f32_16x16x32_bf16(k0, qf[1][0], sB[n], 0, 0, 0);
      sB[n] = __builtin_amdgcn_mfma_f32_16x16x32_bf16(k1, qf[1][1], sB[n], 0, 0, 0);
    }
    __builtin_amdgcn_s_setprio(0);

    // ---- online softmax, half A (per-lane row qt+q) ----
    float alphaA, alphaB;
    {
      float t0 = fmaxf(fmaxf(sA[0][0], sA[0][1]), fmaxf(sA[0][2], sA[0][3]));
      float t1 = fmaxf(fmaxf(sA[1][0], sA[1][1]), fmaxf(sA[1][2], sA[1][3]));
      float t2 = fmaxf(fmaxf(sA[2][0], sA[2][1]), fmaxf(sA[2][2], sA[2][3]));
      float t3 = fmaxf(fmaxf(sA[3][0], sA[3][1]), fmaxf(sA[3][2], sA[3][3]));
      float tm = fmaxf(fmaxf(t0, t1), fmaxf(t2, t3));
      tm = fmaxf(tm, __shfl_xor(tm, 16, 64));
      tm = fmaxf(tm, __shfl_xor(tm, 32, 64));
      float mnew = fmaxf(mA, tm);
      alphaA = __expf((mA - mnew) * 0.125f);
      mA = mnew;
#pragma unroll
      for (int n = 0; n < 4; n++)
#pragma unroll
        for (int i = 0; i < 4; i++) sA[n][i] = __expf((sA[n][i] - mnew) * 0.125f);
      float r0 = (sA[0][0] + sA[0][1]) + (sA[0][2] + sA[0][3]);
      float r1 = (sA[1][0] + sA[1][1]) + (sA[1][2] + sA[1][3]);
      float r2 = (sA[2][0] + sA[2][1]) + (sA[2][2] + sA[2][3]);
      float r3 = (sA[3][0] + sA[3][1]) + (sA[3][2] + sA[3][3]);
      float rs = (r0 + r1) + (r2 + r3);
      rs += __shfl_xor(rs, 16, 64);
      rs += __shfl_xor(rs, 32, 64);
      lA = lA * alphaA + rs;
#pragma unroll
      for (int n = 0; n < 4; n++) {
        uint32_t w0 = cvtpk(sA[n][0], sA[n][1]);
        uint32_t w1 = cvtpk(sA[n][2], sA[n][3]);
        *(uint2*)(Pw + q * 72 + n * 16 + g * 4) = make_uint2(w0, w1);
      }
    }
    // ---- half B ----
    {
      float t0 = fmaxf(fmaxf(sB[0][0], sB[0][1]), fmaxf(sB[0][2], sB[0][3]));
      float t1 = fmaxf(fmaxf(sB[1][0], sB[1][1]), fmaxf(sB[1][2], sB[1][3]));
      float t2 = fmaxf(fmaxf(sB[2][0], sB[2][1]), fmaxf(sB[2][2], sB[2][3]));
      float t3 = fmaxf(fmaxf(sB[3][0], sB[3][1]), fmaxf(sB[3][2], sB[3][3]));
      float tm = fmaxf(fmaxf(t0, t1), fmaxf(t2, t3));
      tm = fmaxf(tm, __shfl_xor(tm, 16, 64));
      tm = fmaxf(tm, __shfl_xor(tm, 32, 64));
      float mnew = fmaxf(mB, tm);
      alphaB = __expf((mB - mnew) * 0.125f);
      mB = mnew;
#pragma unroll
      for (int n = 0; n < 4; n++)
#pragma unroll
        for (int i = 0; i < 4; i++) sB[n][i] = __expf((sB[n][i] - mnew) * 0.125f);
      float r0 = (sB[0][0] + sB[0][1]) + (sB[0][2] + sB[0][3]);
      float r1 = (sB[1][0] + sB[1][1]) + (sB[1][2] + sB[1][3]);
      float r2 = (sB[2][0] + sB[2][1]) + (sB[2][2] + sB[2][3]);
      float r3 = (sB[3][0] + sB[3][1]) + (sB[3][2] + sB[3][3]);
      float rs = (r0 + r1) + (r2 + r3);
      rs += __shfl_xor(rs, 16, 64);
      rs += __shfl_xor(rs, 32, 64);
      lB = lB * alphaB + rs;
#pragma unroll
      for (int n = 0; n < 4; n++) {
        uint32_t w0 = cvtpk(sB[n][0], sB[n][1]);
        uint32_t w1 = cvtpk(sB[n][2], sB[n][3]);
        *(uint2*)(Pw + (16 + q) * 72 + n * 16 + g * 4) = make_uint2(w0, w1);
      }
    }

    // rescale O
#pragma unroll
    for (int n = 0; n < 4; n++)
#pragma unroll
      for (int i = 0; i < 4; i++) {
        oA[n][i] *= alphaA;
        oB[n][i] *= alphaB;
      }

    // PV: O^T += V^T-frag x P^T-frag
    short8 pA[2], pB[2];
#pragma unroll
    for (int hh = 0; hh < 2; hh++) {
      pA[hh] = *(const short8*)(Pw + q * 72 + hh * 32 + g * 8);
      pB[hh] = *(const short8*)(Pw + (16 + q) * 72 + hh * 32 + g * 8);
    }
    __builtin_amdgcn_s_setprio(1);
#pragma unroll
    for (int n = 0; n < 4; n++) {
      int row = n * 16 + q;
      short8 v0 = *(const short8*)(Vb + row * 64 + ((g ^ (q & 7)) * 8));
      short8 v1 = *(const short8*)(Vb + row * 64 + (((4 + g) ^ (q & 7)) * 8));
      oA[n] = __builtin_amdgcn_mfma_f32_16x16x32_bf16(v0, pA[0], oA[n], 0, 0, 0);
      oA[n] = __builtin_amdgcn_mfma_f32_16x16x32_bf16(v1, pA[1], oA[n], 0, 0, 0);
      oB[n] = __builtin_amdgcn_mfma_f32_16x16x32_bf16(v0, pB[0], oB[n], 0, 0, 0);
      oB[n] = __builtin_amdgcn_mfma_f32_16x16x32_bf16(v1, pB[1], oB[n], 0, 0, 0);
    }
    __builtin_amdgcn_s_setprio(0);

    __syncthreads();   // single drain per tile: staged loads had full compute to land
  }

  float invA = 1.f / lA, invB = 1.f / lB;
  u16t* crowA = ctx + (size_t)(b * 1024 + qt + q) * 768 + h * 64;
  u16t* crowB = ctx + (size_t)(b * 1024 + qt + 16 + q) * 768 + h * 64;
#pragma unroll
  for (int n = 0; n < 4; n++) {
    uint32_t a0 = (uint32_t)f2bf(oA[n][0] * invA) | ((uint32_t)f2bf(oA[n][1] * invA) << 16);
    uint32_t a1 = (uint32_t)f2bf(oA[n][2] * invA) | ((uint32_t)f2bf(oA[n][3] * invA) << 16);
    *(uint32_t*)(crowA + n * 16 + g * 4) = a0;
    *(uint32_t*)(crowA + n * 16 + g * 4 + 2) = a1;
    uint32_t b0 = (uint32_t)f2bf(oB[n][0] * invB) | ((uint32_t)f2bf(oB[n][1] * invB) << 16);
    uint32_t b1 = (uint32_t)f2bf(oB[n][2] * invB) | ((uint32_t)f2bf(oB[n][3] * invB) << 16);
    *(uint32_t*)(crowB + n * 16 + g * 4) = b0;
    *(uint32_t*)(crowB + n * 16 + g * 4 + 2) = b1;
  }
}

// ---------- launch ----------
extern "C" void kernel_launch(void* const* d_in, const int* in_sizes, int n_in,
                              void* d_out, int out_size, void* d_ws, size_t ws_size,
                              hipStream_t stream) {
  const float* x      = (const float*)d_in[0];
  const float* ln1_g  = (const float*)d_in[1];
  const float* ln1_b  = (const float*)d_in[2];
  const float* qkv_w  = (const float*)d_in[3];
  const float* proj_w = (const float*)d_in[4];
  const float* proj_b = (const float*)d_in[5];
  const float* ln2_g  = (const float*)d_in[6];
  const float* ln2_b  = (const float*)d_in[7];
  const float* fc1_w  = (const float*)d_in[8];
  const float* fc1_b  = (const float*)d_in[9];
  const float* fc2_w  = (const float*)d_in[10];
  const float* fc2_b  = (const float*)d_in[11];

  char* ws = (char*)d_ws;
  u16t* h1   = (u16t*)(ws + 0);           // 8192x768 bf16 (ln1 out; REUSED as vt; then ln2 out)
  u16t* qkvb = (u16t*)(ws + 12582912);    // 8192x2304 bf16
  u16t* ctx  = (u16t*)(ws + 50331648);    // 8192x768 bf16
  float* x2  = (float*)(ws + 62914560);   // 8192x768 f32
  u16t* hid  = (u16t*)(ws + 88080384);    // 8192x3072 bf16
  u16t* wq   = (u16t*)(ws + 138412032);   // 2304x768 bf16
  u16t* wp   = (u16t*)(ws + 141950976);   // 768x768 bf16
  u16t* w1   = (u16t*)(ws + 143130624);   // 3072x768 bf16
  u16t* w2   = (u16t*)(ws + 147849216);   // 768x3072 bf16
  u16t* vtb  = h1;                        // 96x64x1024 bf16 = same 12.58MB, lifetime-disjoint
  float* out = (float*)d_out;

  cvt_bf16_kernel<<<864, 256, 0, stream>>>(qkv_w, wq, 221184);
  cvt_bf16_kernel<<<288, 256, 0, stream>>>(proj_w, wp, 73728);
  cvt_bf16_kernel<<<1152, 256, 0, stream>>>(fc1_w, w1, 294912);
  cvt_bf16_kernel<<<1152, 256, 0, stream>>>(fc2_w, w2, 294912);

  ln_kernel<<<8192, 256, 0, stream>>>(x, ln1_g, ln1_b, h1);
  gemm_bt<0, 128, 3><<<dim3(18, 64), 256, 0, stream>>>(h1, wq, qkvb, nullptr, nullptr, 8192, 2304, 768);
  vtrans_kernel<<<dim3(96, 16), 256, 0, stream>>>(qkvb, vtb);
  attn_kernel<<<768, 256, 0, stream>>>(qkvb, vtb, ctx);
  gemm_bt<1, 64, 4><<<dim3(6, 128), 256, 0, stream>>>(ctx, wp, x2, proj_b, x, 8192, 768, 768);
  ln_kernel<<<8192, 256, 0, stream>>>(x2, ln2_g, ln2_b, h1);
  gemm_bt<2, 128, 3><<<dim3(24, 64), 256, 0, stream>>>(h1, w1, hid, fc1_b, nullptr, 8192, 3072, 768);
  gemm_bt<1, 64, 4><<<dim3(6, 128), 256, 0, stream>>>(hid, w2, out, fc2_b, x2, 8192, 768, 3072);
}